// Round 12
// baseline (105.865 us; speedup 1.0000x reference)
//
#include <hip/hip_runtime.h>

typedef __attribute__((ext_vector_type(8))) short short8;
typedef __attribute__((ext_vector_type(4))) float f32x4;

typedef __attribute__((address_space(1))) const unsigned gas_u32;
typedef __attribute__((address_space(3))) unsigned las_u32;

static __device__ __forceinline__ void g2l16(const void* g, void* l) {
  __builtin_amdgcn_global_load_lds((gas_u32*)g, (las_u32*)l, 16, 0, 0);
}

static __device__ __forceinline__ short f2bf(float f) {
  union { float f; unsigned u; } v; v.f = f;
  unsigned r = (v.u + 0x7FFFu + ((v.u >> 16) & 1u)) >> 16;   // RNE
  return (short)r;
}

#define MF(a_, b_, c_) __builtin_amdgcn_mfma_f32_16x16x32_bf16(a_, b_, c_, 0, 0, 0)

// ---- x fp32 -> bf16 into zero-padded xbp[32][34][34][128], 8 elems/thread ----
static __device__ __forceinline__ void xcvt_body(const float* __restrict__ x,
                                                 short* __restrict__ xbp, int i) {
  int c8 = i & 15;
  int t = i >> 4;
  int wp = t % 34, t2 = t / 34;
  int hp = t2 % 34, b = t2 / 34;
  short8 o = {};
  if (hp >= 1 && hp <= 32 && wp >= 1 && wp <= 32) {
    const f32x4* s = (const f32x4*)(x + (((size_t)((b << 5) + hp - 1) << 5) + (wp - 1)) * 128 + c8 * 8);
    f32x4 a = s[0], bb2 = s[1];
    o[0] = f2bf(a[0]); o[1] = f2bf(a[1]); o[2] = f2bf(a[2]); o[3] = f2bf(a[3]);
    o[4] = f2bf(bb2[0]); o[5] = f2bf(bb2[1]); o[6] = f2bf(bb2[2]); o[7] = f2bf(bb2[3]);
  }
  ((short8*)xbp)[i] = o;
}

// ---- weight prep: maskmul | tmask(k1,m1) | tmask(k2,m2) | xcvt share ----
__global__ __launch_bounds__(256) void k_prepw(const float* __restrict__ k0f,
                                               const float* __restrict__ m0f,
                                               const float* __restrict__ scf,
                                               const float* __restrict__ k1f,
                                               const float* __restrict__ m1f,
                                               const float* __restrict__ k2f,
                                               const float* __restrict__ m2f,
                                               short* __restrict__ w1b,
                                               short* __restrict__ w2T,
                                               short* __restrict__ w3T,
                                               const float* __restrict__ x,
                                               short* __restrict__ xbp) {
  __shared__ float tile[32][33];
  const int bb = blockIdx.x, tid = threadIdx.x;
  if (bb < 648) {
    int i = bb * 256 + tid;
    float s = scf[0];
    const f32x4* kk = (const f32x4*)k0f + (size_t)i * 2;
    const f32x4* mm = (const f32x4*)m0f + (size_t)i * 2;
    f32x4 a0 = kk[0], a1 = kk[1], b0 = mm[0], b1 = mm[1];
    short8 o;
    o[0] = f2bf(a0[0] * b0[0] * s); o[1] = f2bf(a0[1] * b0[1] * s);
    o[2] = f2bf(a0[2] * b0[2] * s); o[3] = f2bf(a0[3] * b0[3] * s);
    o[4] = f2bf(a1[0] * b1[0] * s); o[5] = f2bf(a1[1] * b1[1] * s);
    o[6] = f2bf(a1[2] * b1[2] * s); o[7] = f2bf(a1[3] * b1[3] * s);
    ((short8*)w1b)[i] = o;
  } else if (bb < 1480) {
    const float *kf, *mf; short* outp; int D, F, idx;
    if (bb < 1224) { kf = k1f; mf = m1f; outp = w2T; D = 1152; F = 512; idx = bb - 648; }
    else           { kf = k2f; mf = m2f; outp = w3T; D = 512;  F = 512; idx = bb - 1224; }
    int f0 = (idx & 15) * 32, d0 = (idx >> 4) * 32;
    int tx = tid & 31, ty = tid >> 5;
#pragma unroll
    for (int i = 0; i < 4; ++i) {
      int d = d0 + ty + i * 8;
      size_t ix = (size_t)d * F + f0 + tx;
      tile[ty + i * 8][tx] = kf[ix] * mf[ix];
    }
    __syncthreads();
#pragma unroll
    for (int i = 0; i < 4; ++i) {
      int f = f0 + ty + i * 8;
      outp[(size_t)f * D + d0 + tx] = f2bf(tile[tx][ty + i * 8]);
    }
  } else {
    xcvt_body(x, xbp, (bb - 1480) * 256 + tid);   // xcvt blocks 0..767
  }
}

// ---- bf16 GEMM 64x64 tiles, BK=128 double-buffered prefetch (blocks < 144),
//      merged with x-convert (blocks >= 144) ----
__global__ __launch_bounds__(256) void k_gemmx(const short* __restrict__ A,
                                               const short* __restrict__ BT,
                                               short* __restrict__ C, int M, int N, int K,
                                               const float* __restrict__ x,
                                               short* __restrict__ xbp, int xoff) {
  __shared__ __align__(16) short As[2][64][128];   // 32 KiB
  __shared__ __align__(16) short Bs[2][64][128];   // 32 KiB
  if (blockIdx.x >= 144) {
    xcvt_body(x, xbp, (xoff + (int)blockIdx.x - 144) * 256 + (int)threadIdx.x);
    return;
  }
  const int ntiles = N >> 6;
  const int m0 = (blockIdx.x / ntiles) << 6, n0 = (blockIdx.x % ntiles) << 6;
  const int tid = threadIdx.x;
  const int lane = tid & 63, wv = tid >> 6;
  const int wr = (wv >> 1) * 32, wc = (wv & 1) * 32;
  const int lr = lane & 15, lh = lane >> 4;

  const int rr = tid >> 4, sl = tid & 15;
  const int swz = sl ^ (rr & 7);
  const unsigned aOff = (unsigned)(m0 + rr) * K + swz * 8;
  const unsigned bOff = (unsigned)(n0 + rr) * K + swz * 8;
  const int ldsRow = 4 * wv;

  f32x4 acc[2][2] = {};

#define GST(buf_, kt_) do { \
    _Pragma("unroll") for (int j = 0; j < 4; ++j) \
      g2l16(A + aOff + (unsigned)j * 16u * (unsigned)K + (unsigned)(kt_) * 128u, \
            &As[buf_][j * 16 + ldsRow][0]); \
    _Pragma("unroll") for (int j = 0; j < 4; ++j) \
      g2l16(BT + bOff + (unsigned)j * 16u * (unsigned)K + (unsigned)(kt_) * 128u, \
            &Bs[buf_][j * 16 + ldsRow][0]); \
  } while (0)

  const int nk = K >> 7;
  GST(0, 0);
  asm volatile("s_waitcnt vmcnt(0)" ::: "memory");
  __builtin_amdgcn_s_barrier();

  for (int kt = 0; kt < nk; ++kt) {
    const int cur = kt & 1;
    if (kt + 1 < nk) { if (cur) GST(0, kt + 1); else GST(1, kt + 1); }
#pragma unroll
    for (int ks = 0; ks < 4; ++ks) {
      short8 af[2], bf[2];
#pragma unroll
      for (int i = 0; i < 2; ++i)
        af[i] = *(const short8*)&As[cur][wr + i * 16 + lr][((ks * 4 + lh) ^ (lr & 7)) * 8];
#pragma unroll
      for (int i = 0; i < 2; ++i)
        bf[i] = *(const short8*)&Bs[cur][wc + i * 16 + lr][((ks * 4 + lh) ^ (lr & 7)) * 8];
#pragma unroll
      for (int mi = 0; mi < 2; ++mi)
#pragma unroll
        for (int ni = 0; ni < 2; ++ni)
          acc[mi][ni] = MF(af[mi], bf[ni], acc[mi][ni]);
    }
    if (kt + 1 < nk) asm volatile("s_waitcnt vmcnt(0)" ::: "memory");
    __builtin_amdgcn_s_barrier();
  }
#pragma unroll
  for (int mi = 0; mi < 2; ++mi) {
    const int row = m0 + wr + mi * 16 + lh * 4;
#pragma unroll
    for (int ni = 0; ni < 2; ++ni) {
      const int col = n0 + wc + ni * 16 + lr;
#pragma unroll
      for (int q = 0; q < 4; ++q)
        C[(size_t)(row + q) * N + col] = f2bf(acc[mi][ni][q]);
    }
  }
#undef GST
}

// ======== conv: 256x128 tile, 4 waves x (128x64), A DIRECT from global, B via LDS ========
// out[32768][512] = im2col(xbp)[32768][1152] @ wT[512][1152]^T + bias
// Staging-BW fix: only B (147 MB total) goes through global_load_lds; A-fragments
// are loaded straight from padded xbp into registers (fragment rows are
// lane-aligned: lane lr -> row mf*16+lr, lanes lh -> contiguous 64B). B is
// double-buffered (32 KiB LDS) -> ONE barrier per K-tile; compiler schedules the
// straight-line 64-MFMA tile body with fine-grained waits.
#define RD_B(buf_, nf_, ks_) \
  (*(const short8*)&Bs[buf_][wc * 64 + (nf_) * 16 + lr][(((ks_) * 4 + lh) ^ (lr & 7)) * 8])

// stage all B (128 rows) of K-tile tt into buf, 4 ops/thread
#define STAGE_B(buf_, tt_) do { \
  const int tc_ = (tt_) > 17 ? 17 : (tt_); \
  g2l16(wT + bBase +          tc_ * 64, &Bs[buf_][     ldsB][0]); \
  g2l16(wT + bBase +  36864 + tc_ * 64, &Bs[buf_][32 + ldsB][0]); \
  g2l16(wT + bBase +  73728 + tc_ * 64, &Bs[buf_][64 + ldsB][0]); \
  g2l16(wT + bBase + 110592 + tc_ * 64, &Bs[buf_][96 + ldsB][0]); } while (0)

__global__ __launch_bounds__(256, 2) void k_conv(const short* __restrict__ xbp,
                                                 const short* __restrict__ wT,
                                                 const float* __restrict__ bias,
                                                 float* __restrict__ out) {
  __shared__ __align__(16) short Bs[2][128][64];   // 32 KiB (double-buffered B)
  int bid = blockIdx.x;
  bid = (bid & 7) * 64 + (bid >> 3);            // bijective XCD swizzle (512 % 8 == 0)
  const int mt = bid >> 2, nt = bid & 3;
  const int m0 = mt << 8, n0 = nt << 7;
  const int tid = threadIdx.x;
  const int lane = tid & 63, wid = tid >> 6;    // 4 waves: 2M x 2N
  const int wr = wid >> 1, wc = wid & 1;
  const int lr = lane & 15, lh = lane >> 4;

  f32x4 acc[8][4] = {};

  // B staging geometry (as before): each g2l16 = 32 LDS rows; pre-swizzled source
  const int rsub = tid >> 3;                    // 0..31
  const int sw = (tid & 7) ^ (rsub & 7);        // pre-swizzled 16B slot
  const int ldsB = wid * 8;                     // wave-uniform LDS row base
  const unsigned bBase = (unsigned)(n0 + rsub) * 1152 + sw * 8;

  // A direct-load fragment bases: row = m0 + wr*128 + mf*16 + lr ; lane k-off lh*8
  unsigned aFB[8];
#pragma unroll
  for (int mf = 0; mf < 8; ++mf) {
    const int R = m0 + wr * 128 + mf * 16 + lr;
    const int b = R >> 10, h0 = (R >> 5) & 31, w = R & 31;
    aFB[mf] = (unsigned)((b * 34 + h0) * 34 + w) * 128 + lh * 8;
  }

  // prologue: stage B(0) into buf0, drain, barrier
  STAGE_B(0, 0);
  asm volatile("s_waitcnt vmcnt(0)" ::: "memory");
  __builtin_amdgcn_s_barrier();

  for (int t = 0; t < 18; ++t) {
    const int cur = t & 1;
    const int khw = t >> 1;
    const int kh = (khw * 11) >> 5, kw = khw - kh * 3;
    const unsigned ao = (unsigned)((kh * 34 + kw) * 128 + ((t & 1) << 6));

    // issue next tile's B staging early (into the other buffer; no WAR)
    if (cur) STAGE_B(0, t + 1); else STAGE_B(1, t + 1);

    // B fragments from LDS (current buffer)
    short8 bfr[4][2];
#pragma unroll
    for (int nf = 0; nf < 4; ++nf) {
      bfr[nf][0] = RD_B(cur, nf, 0);
      bfr[nf][1] = RD_B(cur, nf, 1);
    }

    // ks = 0: 8 direct A-frag loads + 32 independent MFMAs
    {
      short8 af[8];
#pragma unroll
      for (int mf = 0; mf < 8; ++mf)
        af[mf] = *(const short8*)(xbp + aFB[mf] + ao);
      __builtin_amdgcn_s_setprio(1);
#pragma unroll
      for (int mf = 0; mf < 8; ++mf) {
        acc[mf][0] = MF(af[mf], bfr[0][0], acc[mf][0]);
        acc[mf][1] = MF(af[mf], bfr[1][0], acc[mf][1]);
        acc[mf][2] = MF(af[mf], bfr[2][0], acc[mf][2]);
        acc[mf][3] = MF(af[mf], bfr[3][0], acc[mf][3]);
      }
      __builtin_amdgcn_s_setprio(0);
    }
    // ks = 1: 8 direct A-frag loads + 32 MFMAs
    {
      short8 af[8];
#pragma unroll
      for (int mf = 0; mf < 8; ++mf)
        af[mf] = *(const short8*)(xbp + aFB[mf] + ao + 32);
      __builtin_amdgcn_s_setprio(1);
#pragma unroll
      for (int mf = 0; mf < 8; ++mf) {
        acc[mf][0] = MF(af[mf], bfr[0][1], acc[mf][0]);
        acc[mf][1] = MF(af[mf], bfr[1][1], acc[mf][1]);
        acc[mf][2] = MF(af[mf], bfr[2][1], acc[mf][2]);
        acc[mf][3] = MF(af[mf], bfr[3][1], acc[mf][3]);
      }
      __builtin_amdgcn_s_setprio(0);
    }

    // next tile's B writes must be visible to all waves before its reads
    asm volatile("s_waitcnt vmcnt(0)" ::: "memory");
    __builtin_amdgcn_s_barrier();
  }

  // epilogue: fp32 + bias
  const int orow = m0 + wr * 128, ocol = n0 + wc * 64;
#pragma unroll
  for (int mf = 0; mf < 8; ++mf) {
    const int row = orow + mf * 16 + lh * 4;
#pragma unroll
    for (int nf = 0; nf < 4; ++nf) {
      const int col = ocol + nf * 16 + lr;
      const float bv = bias[col];
#pragma unroll
      for (int q = 0; q < 4; ++q)
        out[(size_t)(row + q) * 512 + col] = acc[mf][nf][q] + bv;
    }
  }
}

extern "C" void kernel_launch(void* const* d_in, const int* in_sizes, int n_in,
                              void* d_out, int out_size, void* d_ws, size_t ws_size,
                              hipStream_t stream) {
  (void)in_sizes; (void)n_in; (void)out_size; (void)ws_size;
  const float* x    = (const float*)d_in[0];
  const float* k0   = (const float*)d_in[1];
  const float* k1   = (const float*)d_in[2];
  const float* k2   = (const float*)d_in[3];
  const float* m0   = (const float*)d_in[4];
  const float* m1   = (const float*)d_in[5];
  const float* m2   = (const float*)d_in[6];
  const float* sc   = (const float*)d_in[7];
  const float* bias = (const float*)d_in[8];
  float* out = (float*)d_out;
  char* ws = (char*)d_ws;

  short* xbp = (short*)(ws);              // 32*34*34*128 bf16 = 9,469,952 B
  short* w1b = (short*)(ws + 9469952);    // 1152*1152 bf16    = 2,654,208 B
  short* w2T = (short*)(ws + 12124160);   // 512*1152 bf16     = 1,179,648 B
  short* w3T = (short*)(ws + 13303808);   // 512*512 bf16      =   524,288 B
  short* A1b = (short*)(ws + 13828096);   // 1152*512 bf16     = 1,179,648 B
  short* wET = (short*)(ws + 15007744);   // 512*1152 bf16     = 1,179,648 B

  // xcvt split: 768 blocks (prepw) + 772 (gemm1) + 772 (gemm2) = 2312 total
  k_prepw<<<2248, 256, 0, stream>>>(k0, m0, sc, k1, m1, k2, m2, w1b, w2T, w3T, x, xbp);
  k_gemmx<<<916, 256, 0, stream>>>(w1b, w2T, A1b, 1152, 512, 1152, x, xbp, 768);
  k_gemmx<<<916, 256, 0, stream>>>(w3T, A1b, wET, 512, 1152, 512, x, xbp, 1540);
  k_conv<<<512, 256, 0, stream>>>(xbp, wET, bias, out);
}

// Round 13
// 71.844 us; speedup vs baseline: 1.4736x; 1.4736x over previous
//
#include <hip/hip_runtime.h>

typedef __attribute__((ext_vector_type(8))) short short8;
typedef __attribute__((ext_vector_type(4))) float f32x4;

typedef __attribute__((address_space(1))) const unsigned gas_u32;
typedef __attribute__((address_space(3))) unsigned las_u32;

static __device__ __forceinline__ void g2l16(const void* g, void* l) {
  __builtin_amdgcn_global_load_lds((gas_u32*)g, (las_u32*)l, 16, 0, 0);
}

static __device__ __forceinline__ short f2bf(float f) {
  union { float f; unsigned u; } v; v.f = f;
  unsigned r = (v.u + 0x7FFFu + ((v.u >> 16) & 1u)) >> 16;   // RNE
  return (short)r;
}

#define MF(a_, b_, c_) __builtin_amdgcn_mfma_f32_16x16x32_bf16(a_, b_, c_, 0, 0, 0)

// ---- x fp32 -> bf16 into zero-padded xbp[32][34][34][128], 8 elems/thread ----
static __device__ __forceinline__ void xcvt_body(const float* __restrict__ x,
                                                 short* __restrict__ xbp, int i) {
  int c8 = i & 15;
  int t = i >> 4;
  int wp = t % 34, t2 = t / 34;
  int hp = t2 % 34, b = t2 / 34;
  short8 o = {};
  if (hp >= 1 && hp <= 32 && wp >= 1 && wp <= 32) {
    const f32x4* s = (const f32x4*)(x + (((size_t)((b << 5) + hp - 1) << 5) + (wp - 1)) * 128 + c8 * 8);
    f32x4 a = s[0], bb2 = s[1];
    o[0] = f2bf(a[0]); o[1] = f2bf(a[1]); o[2] = f2bf(a[2]); o[3] = f2bf(a[3]);
    o[4] = f2bf(bb2[0]); o[5] = f2bf(bb2[1]); o[6] = f2bf(bb2[2]); o[7] = f2bf(bb2[3]);
  }
  ((short8*)xbp)[i] = o;
}

// ---- weight prep: maskmul | tmask(k1,m1) | tmask(k2,m2) | xcvt share ----
__global__ __launch_bounds__(256) void k_prepw(const float* __restrict__ k0f,
                                               const float* __restrict__ m0f,
                                               const float* __restrict__ scf,
                                               const float* __restrict__ k1f,
                                               const float* __restrict__ m1f,
                                               const float* __restrict__ k2f,
                                               const float* __restrict__ m2f,
                                               short* __restrict__ w1b,
                                               short* __restrict__ w2T,
                                               short* __restrict__ w3T,
                                               const float* __restrict__ x,
                                               short* __restrict__ xbp) {
  __shared__ float tile[32][33];
  const int bb = blockIdx.x, tid = threadIdx.x;
  if (bb < 648) {
    int i = bb * 256 + tid;
    float s = scf[0];
    const f32x4* kk = (const f32x4*)k0f + (size_t)i * 2;
    const f32x4* mm = (const f32x4*)m0f + (size_t)i * 2;
    f32x4 a0 = kk[0], a1 = kk[1], b0 = mm[0], b1 = mm[1];
    short8 o;
    o[0] = f2bf(a0[0] * b0[0] * s); o[1] = f2bf(a0[1] * b0[1] * s);
    o[2] = f2bf(a0[2] * b0[2] * s); o[3] = f2bf(a0[3] * b0[3] * s);
    o[4] = f2bf(a1[0] * b1[0] * s); o[5] = f2bf(a1[1] * b1[1] * s);
    o[6] = f2bf(a1[2] * b1[2] * s); o[7] = f2bf(a1[3] * b1[3] * s);
    ((short8*)w1b)[i] = o;
  } else if (bb < 1480) {
    const float *kf, *mf; short* outp; int D, F, idx;
    if (bb < 1224) { kf = k1f; mf = m1f; outp = w2T; D = 1152; F = 512; idx = bb - 648; }
    else           { kf = k2f; mf = m2f; outp = w3T; D = 512;  F = 512; idx = bb - 1224; }
    int f0 = (idx & 15) * 32, d0 = (idx >> 4) * 32;
    int tx = tid & 31, ty = tid >> 5;
#pragma unroll
    for (int i = 0; i < 4; ++i) {
      int d = d0 + ty + i * 8;
      size_t ix = (size_t)d * F + f0 + tx;
      tile[ty + i * 8][tx] = kf[ix] * mf[ix];
    }
    __syncthreads();
#pragma unroll
    for (int i = 0; i < 4; ++i) {
      int f = f0 + ty + i * 8;
      outp[(size_t)f * D + d0 + tx] = f2bf(tile[tx][ty + i * 8]);
    }
  } else {
    xcvt_body(x, xbp, (bb - 1480) * 256 + tid);   // xcvt blocks 0..767
  }
}

// ---- bf16 GEMM 64x64 tiles, BK=128 double-buffered prefetch (blocks < 144),
//      merged with x-convert (blocks >= 144) ----
__global__ __launch_bounds__(256) void k_gemmx(const short* __restrict__ A,
                                               const short* __restrict__ BT,
                                               short* __restrict__ C, int M, int N, int K,
                                               const float* __restrict__ x,
                                               short* __restrict__ xbp, int xoff) {
  __shared__ __align__(16) short As[2][64][128];   // 32 KiB
  __shared__ __align__(16) short Bs[2][64][128];   // 32 KiB
  if (blockIdx.x >= 144) {
    xcvt_body(x, xbp, (xoff + (int)blockIdx.x - 144) * 256 + (int)threadIdx.x);
    return;
  }
  const int ntiles = N >> 6;
  const int m0 = (blockIdx.x / ntiles) << 6, n0 = (blockIdx.x % ntiles) << 6;
  const int tid = threadIdx.x;
  const int lane = tid & 63, wv = tid >> 6;
  const int wr = (wv >> 1) * 32, wc = (wv & 1) * 32;
  const int lr = lane & 15, lh = lane >> 4;

  const int rr = tid >> 4, sl = tid & 15;
  const int swz = sl ^ (rr & 7);
  const unsigned aOff = (unsigned)(m0 + rr) * K + swz * 8;
  const unsigned bOff = (unsigned)(n0 + rr) * K + swz * 8;
  const int ldsRow = 4 * wv;

  f32x4 acc[2][2] = {};

#define GST(buf_, kt_) do { \
    _Pragma("unroll") for (int j = 0; j < 4; ++j) \
      g2l16(A + aOff + (unsigned)j * 16u * (unsigned)K + (unsigned)(kt_) * 128u, \
            &As[buf_][j * 16 + ldsRow][0]); \
    _Pragma("unroll") for (int j = 0; j < 4; ++j) \
      g2l16(BT + bOff + (unsigned)j * 16u * (unsigned)K + (unsigned)(kt_) * 128u, \
            &Bs[buf_][j * 16 + ldsRow][0]); \
  } while (0)

  const int nk = K >> 7;
  GST(0, 0);
  asm volatile("s_waitcnt vmcnt(0)" ::: "memory");
  __builtin_amdgcn_s_barrier();

  for (int kt = 0; kt < nk; ++kt) {
    const int cur = kt & 1;
    if (kt + 1 < nk) { if (cur) GST(0, kt + 1); else GST(1, kt + 1); }
#pragma unroll
    for (int ks = 0; ks < 4; ++ks) {
      short8 af[2], bf[2];
#pragma unroll
      for (int i = 0; i < 2; ++i)
        af[i] = *(const short8*)&As[cur][wr + i * 16 + lr][((ks * 4 + lh) ^ (lr & 7)) * 8];
#pragma unroll
      for (int i = 0; i < 2; ++i)
        bf[i] = *(const short8*)&Bs[cur][wc + i * 16 + lr][((ks * 4 + lh) ^ (lr & 7)) * 8];
#pragma unroll
      for (int mi = 0; mi < 2; ++mi)
#pragma unroll
        for (int ni = 0; ni < 2; ++ni)
          acc[mi][ni] = MF(af[mi], bf[ni], acc[mi][ni]);
    }
    if (kt + 1 < nk) asm volatile("s_waitcnt vmcnt(0)" ::: "memory");
    __builtin_amdgcn_s_barrier();
  }
#pragma unroll
  for (int mi = 0; mi < 2; ++mi) {
    const int row = m0 + wr + mi * 16 + lh * 4;
#pragma unroll
    for (int ni = 0; ni < 2; ++ni) {
      const int col = n0 + wc + ni * 16 + lr;
#pragma unroll
      for (int q = 0; q < 4; ++q)
        C[(size_t)(row + q) * N + col] = f2bf(acc[mi][ni][q]);
    }
  }
#undef GST
}

// ======== conv: 256x128, 4 waves x (128x64), single-buffer BK=64, REG-STAGING (T14) ========
// out[32768][512] = im2col(xbp)[32768][1152] @ wT[512][1152]^T + bias
// Staging converted from global_load_lds to global->VGPR->ds_write_b128: same
// addresses, same bytes, same WAR windows as R10 (writes execute in the phase
// slots where the g2l16s were issued; every target region's last read was in an
// earlier phase, ordered by that phase's barrier). Loads issue one phase early
// (issue-early / write-late); counted vmcnt per phase (4/4/2/2) by queue walk.
#define RD_A(mf_, ks_) \
  (*(const short8*)&As[wr * 128 + (mf_) * 16 + lr][(((ks_) * 4 + lh) ^ (lr & 7)) * 8])
#define RD_B(nf_, ks_) \
  (*(const short8*)&Bs[wc * 64 + (nf_) * 16 + lr][(((ks_) * 4 + lh) ^ (lr & 7)) * 8])

#define LOADB do { \
  bfr[0][0] = RD_B(0, 0); bfr[0][1] = RD_B(0, 1); \
  bfr[1][0] = RD_B(1, 0); bfr[1][1] = RD_B(1, 1); \
  bfr[2][0] = RD_B(2, 0); bfr[2][1] = RD_B(2, 1); \
  bfr[3][0] = RD_B(3, 0); bfr[3][1] = RD_B(3, 1); } while (0)

// load A quarter q of K-tile tt into 2 regs (rows {32q..+31} of each 128-half)
#define LD_AQ(q_, tt_, ra_, rb_) do { \
  const int tc_ = (tt_) > 17 ? 17 : (tt_); \
  const int khw_ = tc_ >> 1; const int kh_ = (khw_ * 11) >> 5; const int kw_ = khw_ - kh_ * 3; \
  const int ao_ = (kh_ * 34 + kw_) * 128 + ((tc_ & 1) << 6) + (q_) * 4352; \
  ra_ = *(const short8*)(xbp + aBase + ao_); \
  rb_ = *(const short8*)(xbp + aBase + 17408 + ao_); } while (0)

#define WR_AQ(q_, ra_, rb_) do { \
  *(short8*)(AsF + ((q_) * 32) * 64 + dstOff) = ra_; \
  *(short8*)(AsF + (128 + (q_) * 32) * 64 + dstOff) = rb_; } while (0)

#define LD_B(tt_) do { \
  const int tc_ = (tt_) > 17 ? 17 : (tt_); \
  rB0 = *(const short8*)(wT + bBase +          tc_ * 64); \
  rB1 = *(const short8*)(wT + bBase +  36864 + tc_ * 64); \
  rB2 = *(const short8*)(wT + bBase +  73728 + tc_ * 64); \
  rB3 = *(const short8*)(wT + bBase + 110592 + tc_ * 64); } while (0)

#define WR_B do { \
  *(short8*)(BsF + 0 * 2048 + dstOff) = rB0; \
  *(short8*)(BsF + 1 * 2048 + dstOff) = rB1; \
  *(short8*)(BsF + 2 * 2048 + dstOff) = rB2; \
  *(short8*)(BsF + 3 * 2048 + dstOff) = rB3; } while (0)

#define MFMA16(p_) \
  acc[2*(p_)  ][0] = MF(a0k0, bfr[0][0], acc[2*(p_)  ][0]); \
  acc[2*(p_)  ][1] = MF(a0k0, bfr[1][0], acc[2*(p_)  ][1]); \
  acc[2*(p_)  ][2] = MF(a0k0, bfr[2][0], acc[2*(p_)  ][2]); \
  acc[2*(p_)  ][3] = MF(a0k0, bfr[3][0], acc[2*(p_)  ][3]); \
  acc[2*(p_)+1][0] = MF(a1k0, bfr[0][0], acc[2*(p_)+1][0]); \
  acc[2*(p_)+1][1] = MF(a1k0, bfr[1][0], acc[2*(p_)+1][1]); \
  acc[2*(p_)+1][2] = MF(a1k0, bfr[2][0], acc[2*(p_)+1][2]); \
  acc[2*(p_)+1][3] = MF(a1k0, bfr[3][0], acc[2*(p_)+1][3]); \
  acc[2*(p_)  ][0] = MF(a0k1, bfr[0][1], acc[2*(p_)  ][0]); \
  acc[2*(p_)  ][1] = MF(a0k1, bfr[1][1], acc[2*(p_)  ][1]); \
  acc[2*(p_)  ][2] = MF(a0k1, bfr[2][1], acc[2*(p_)  ][2]); \
  acc[2*(p_)  ][3] = MF(a0k1, bfr[3][1], acc[2*(p_)  ][3]); \
  acc[2*(p_)+1][0] = MF(a1k1, bfr[0][1], acc[2*(p_)+1][0]); \
  acc[2*(p_)+1][1] = MF(a1k1, bfr[1][1], acc[2*(p_)+1][1]); \
  acc[2*(p_)+1][2] = MF(a1k1, bfr[2][1], acc[2*(p_)+1][2]); \
  acc[2*(p_)+1][3] = MF(a1k1, bfr[3][1], acc[2*(p_)+1][3]);

#define SBAR __builtin_amdgcn_s_barrier()
#define SCHED0 __builtin_amdgcn_sched_barrier(0)
#define LGKM0 asm volatile("s_waitcnt lgkmcnt(0)" ::: "memory")

__global__ __launch_bounds__(256, 2) void k_conv(const short* __restrict__ xbp,
                                                 const short* __restrict__ wT,
                                                 const float* __restrict__ bias,
                                                 float* __restrict__ out) {
  __shared__ __align__(16) short As[256][64];   // 32 KiB
  __shared__ __align__(16) short Bs[128][64];   // 16 KiB
  int bid = blockIdx.x;
  bid = (bid & 7) * 64 + (bid >> 3);            // bijective XCD swizzle (512 % 8 == 0)
  const int mt = bid >> 2, nt = bid & 3;
  const int m0 = mt << 8, n0 = nt << 7;
  const int tid = threadIdx.x;
  const int lane = tid & 63, wid = tid >> 6;    // 4 waves: 2M x 2N
  const int wr = wid >> 1, wc = wid & 1;
  const int lr = lane & 15, lh = lane >> 4;

  f32x4 acc[8][4] = {};
  short8 bfr[4][2];
  short8 rB0, rB1, rB2, rB3;
  short8 rA0a, rA0b, rA1a, rA1b, rA2a, rA2b, rA3a, rA3b;

  // staging geometry: 256 threads x 16B per op = 32 LDS rows; 8 rows/wave
  const int rsub = tid >> 3;                    // 0..31
  const int sw = (tid & 7) ^ (rsub & 7);        // swizzled 16B slot (source side)
  const int ldsA = wid * 8;                     // wave-local LDS row base
  short* AsF = &As[0][0];
  short* BsF = &Bs[0][0];
  const int dstOff = ldsA * 64 + lane * 8;      // shorts; +q*2048 per 32-row chunk

  const int Mb = m0 + rsub;
  const int b = Mb >> 10, h0 = (Mb >> 5) & 31, w = Mb & 31;
  const unsigned aBase = (unsigned)((b * 34 + h0) * 34 + w) * 128 + sw * 8;
  const unsigned bBase = (unsigned)(n0 + rsub) * 1152 + sw * 8;

  // prologue: load+write B(0), AQ0-2(0); leave AQ3(0) loads in flight
  LD_B(0);
  LD_AQ(0, 0, rA0a, rA0b); LD_AQ(1, 0, rA1a, rA1b); LD_AQ(2, 0, rA2a, rA2b);
  asm volatile("s_waitcnt vmcnt(0)" ::: "memory");
  WR_B;
  WR_AQ(0, rA0a, rA0b); WR_AQ(1, rA1a, rA1b); WR_AQ(2, rA2a, rA2b);
  LD_AQ(3, 0, rA3a, rA3b);
  LGKM0;
  SBAR;

  for (int t = 0; t < 18; ++t) {
    const int tn = t + 1;  // clamped inside LD macros (idempotent restage at tail)
    { // ph0: write AQ3(t) [regs from prev ph3/prologue]; issue B(tn) loads
      LD_B(tn);
      SCHED0;
      LOADB;
      short8 a0k0 = RD_A(0, 0), a0k1 = RD_A(0, 1);
      short8 a1k0 = RD_A(1, 0), a1k1 = RD_A(1, 1);
      SBAR;
      LGKM0;
      SCHED0;
      asm volatile("s_waitcnt vmcnt(4)" ::: "memory");   // rA3 ready (B(tn) x4 in flight)
      WR_AQ(3, rA3a, rA3b);
      __builtin_amdgcn_s_setprio(1);
      MFMA16(0)
      __builtin_amdgcn_s_setprio(0);
      LGKM0;
      SBAR;
    }
    { // ph1: write B(tn); issue AQ0,AQ1(tn) loads
      LD_AQ(0, tn, rA0a, rA0b); LD_AQ(1, tn, rA1a, rA1b);
      SCHED0;
      short8 a0k0 = RD_A(2, 0), a0k1 = RD_A(2, 1);
      short8 a1k0 = RD_A(3, 0), a1k1 = RD_A(3, 1);
      SBAR;
      LGKM0;
      SCHED0;
      asm volatile("s_waitcnt vmcnt(4)" ::: "memory");   // rB ready (AQ01 x4 in flight)
      WR_B;
      __builtin_amdgcn_s_setprio(1);
      MFMA16(1)
      __builtin_amdgcn_s_setprio(0);
      LGKM0;
      SBAR;
    }
    { // ph2: write AQ0,AQ1(tn); issue AQ2(tn) loads
      LD_AQ(2, tn, rA2a, rA2b);
      SCHED0;
      short8 a0k0 = RD_A(4, 0), a0k1 = RD_A(4, 1);
      short8 a1k0 = RD_A(5, 0), a1k1 = RD_A(5, 1);
      SBAR;
      LGKM0;
      SCHED0;
      asm volatile("s_waitcnt vmcnt(2)" ::: "memory");   // rA0,rA1 ready (AQ2 x2 in flight)
      WR_AQ(0, rA0a, rA0b); WR_AQ(1, rA1a, rA1b);
      __builtin_amdgcn_s_setprio(1);
      MFMA16(2)
      __builtin_amdgcn_s_setprio(0);
      LGKM0;
      SBAR;
    }
    { // ph3: write AQ2(tn); issue AQ3(tn) loads
      LD_AQ(3, tn, rA3a, rA3b);
      SCHED0;
      short8 a0k0 = RD_A(6, 0), a0k1 = RD_A(6, 1);
      short8 a1k0 = RD_A(7, 0), a1k1 = RD_A(7, 1);
      SBAR;
      LGKM0;
      SCHED0;
      asm volatile("s_waitcnt vmcnt(2)" ::: "memory");   // rA2 ready (AQ3 x2 in flight)
      WR_AQ(2, rA2a, rA2b);
      __builtin_amdgcn_s_setprio(1);
      MFMA16(3)
      __builtin_amdgcn_s_setprio(0);
      LGKM0;
      SBAR;
    }
  }

  // epilogue: fp32 + bias
  const int orow = m0 + wr * 128, ocol = n0 + wc * 64;
#pragma unroll
  for (int mf = 0; mf < 8; ++mf) {
    const int row = orow + mf * 16 + lh * 4;
#pragma unroll
    for (int nf = 0; nf < 4; ++nf) {
      const int col = ocol + nf * 16 + lr;
      const float bv = bias[col];
#pragma unroll
      for (int q = 0; q < 4; ++q)
        out[(size_t)(row + q) * 512 + col] = acc[mf][nf][q] + bv;
    }
  }
}

extern "C" void kernel_launch(void* const* d_in, const int* in_sizes, int n_in,
                              void* d_out, int out_size, void* d_ws, size_t ws_size,
                              hipStream_t stream) {
  (void)in_sizes; (void)n_in; (void)out_size; (void)ws_size;
  const float* x    = (const float*)d_in[0];
  const float* k0   = (const float*)d_in[1];
  const float* k1   = (const float*)d_in[2];
  const float* k2   = (const float*)d_in[3];
  const float* m0   = (const float*)d_in[4];
  const float* m1   = (const float*)d_in[5];
  const float* m2   = (const float*)d_in[6];
  const float* sc   = (const float*)d_in[7];
  const float* bias = (const float*)d_in[8];
  float* out = (float*)d_out;
  char* ws = (char*)d_ws;

  short* xbp = (short*)(ws);              // 32*34*34*128 bf16 = 9,469,952 B
  short* w1b = (short*)(ws + 9469952);    // 1152*1152 bf16    = 2,654,208 B
  short* w2T = (short*)(ws + 12124160);   // 512*1152 bf16     = 1,179,648 B
  short* w3T = (short*)(ws + 13303808);   // 512*512 bf16      =   524,288 B
  short* A1b = (short*)(ws + 13828096);   // 1152*512 bf16     = 1,179,648 B
  short* wET = (short*)(ws + 15007744);   // 512*1152 bf16     = 1,179,648 B

  // xcvt split: 768 blocks (prepw) + 772 (gemm1) + 772 (gemm2) = 2312 total
  k_prepw<<<2248, 256, 0, stream>>>(k0, m0, sc, k1, m1, k2, m2, w1b, w2T, w3T, x, xbp);
  k_gemmx<<<916, 256, 0, stream>>>(w1b, w2T, A1b, 1152, 512, 1152, x, xbp, 768);
  k_gemmx<<<916, 256, 0, stream>>>(w3T, A1b, wET, 512, 1152, 512, x, xbp, 1540);
  k_conv<<<512, 256, 0, stream>>>(xbp, wET, bias, out);
}